// Round 1
// baseline (2508.251 us; speedup 1.0000x reference)
//
#include <hip/hip_runtime.h>
#include <math.h>

#define B_ 4
#define C_ 256
#define N_ 4096   // H*W = 64*64

// ---------------------------------------------------------------------------
// Kernel 1: diag[b*N_+n] = sum_c (f_m+f_d)^2   (the softmax shift, = S[n,n])
// ---------------------------------------------------------------------------
__global__ __launch_bounds__(64) void diag_kernel(const float* __restrict__ fm,
                                                  const float* __restrict__ fd,
                                                  float* __restrict__ diag) {
    int gid = blockIdx.x * 64 + threadIdx.x;      // 0 .. B_*N_-1
    int b  = gid >> 12;                           // /4096
    int nn = gid & (N_ - 1);
    const float* pm = fm + (size_t)b * C_ * N_ + nn;
    const float* pd = fd + (size_t)b * C_ * N_ + nn;
    float s = 0.f;
    #pragma unroll 8
    for (int c = 0; c < C_; ++c) {
        float x = pm[(size_t)c * N_] + pd[(size_t)c * N_];
        s = fmaf(x, x, s);
    }
    diag[gid] = s;
}

// ---------------------------------------------------------------------------
// Kernel 2: w[b*N_+n] = 1 / sum_m exp(S[n,m] - diag[n])
// Block: 512 threads, n-tile = 64 rows, loop m in chunks of 128, K chunks of 64.
// LDS: Xn[64k][64n] (16KB) + Xm[64k][128m] (32KB) = 48KB.
// ---------------------------------------------------------------------------
__global__ __launch_bounds__(512) void lsum_kernel(const float* __restrict__ fm,
                                                   const float* __restrict__ fd,
                                                   const float* __restrict__ diag,
                                                   float* __restrict__ w) {
    __shared__ float Xn[64][64];
    __shared__ float Xm[64][128];
    const int b  = blockIdx.y;
    const int n0 = blockIdx.x * 64;
    const size_t base = (size_t)b * C_ * N_;
    const int t  = threadIdx.x;
    const int tx = t & 31;   // m micro-col group: cols tx*4 .. tx*4+3 (of 128)
    const int ty = t >> 5;   // n micro-row group: rows ty*4 .. ty*4+3 (of 64)

    float dr[4];
    float rs[4] = {0.f, 0.f, 0.f, 0.f};
    #pragma unroll
    for (int i = 0; i < 4; ++i) dr[i] = diag[b * N_ + n0 + ty * 4 + i];

    for (int m0 = 0; m0 < N_; m0 += 128) {
        float s[4][4] = {};
        for (int kc = 0; kc < C_; kc += 64) {
            __syncthreads();
            {   // stage Xn chunk: rows c=kc..kc+63, cols n0..n0+63 (8 elts/thread)
                int col = t & 63;
                int r0  = t >> 6;            // 0..7
                #pragma unroll
                for (int r = r0; r < 64; r += 8) {
                    size_t idx = base + (size_t)(kc + r) * N_ + (n0 + col);
                    Xn[r][col] = fm[idx] + fd[idx];
                }
            }
            {   // stage Xm chunk: rows c=kc..kc+63, cols m0..m0+127 (16 elts/thread)
                int col = t & 127;
                int r0  = t >> 7;            // 0..3
                #pragma unroll
                for (int r = r0; r < 64; r += 4) {
                    size_t idx = base + (size_t)(kc + r) * N_ + (m0 + col);
                    Xm[r][col] = fm[idx] + fd[idx];
                }
            }
            __syncthreads();
            #pragma unroll 8
            for (int k = 0; k < 64; ++k) {
                float4 a  = *(const float4*)(&Xn[k][ty * 4]);
                float4 bb = *(const float4*)(&Xm[k][tx * 4]);
                float av[4] = {a.x, a.y, a.z, a.w};
                float bv[4] = {bb.x, bb.y, bb.z, bb.w};
                #pragma unroll
                for (int i = 0; i < 4; ++i)
                    #pragma unroll
                    for (int j = 0; j < 4; ++j)
                        s[i][j] = fmaf(av[i], bv[j], s[i][j]);
            }
        }
        #pragma unroll
        for (int i = 0; i < 4; ++i) {
            #pragma unroll
            for (int j = 0; j < 4; ++j)
                rs[i] += __expf(s[i][j] - dr[i]);
        }
    }
    // reduce rs over the 32 tx lanes (all within one 32-lane half of the wave)
    #pragma unroll
    for (int off = 1; off < 32; off <<= 1) {
        #pragma unroll
        for (int i = 0; i < 4; ++i)
            rs[i] += __shfl_xor(rs[i], off, 64);
    }
    if (tx == 0) {
        #pragma unroll
        for (int i = 0; i < 4; ++i)
            w[b * N_ + n0 + ty * 4 + i] = 1.0f / rs[i];
    }
}

// ---------------------------------------------------------------------------
// Kernel 3: out[b,c,m] = sum_n f_d[b,c,n] * (w[n]*exp(S[n,m]-diag[n])) + f_d[b,c,m]
// Block: 256 threads, one (batch, 32-wide m-tile). Xm panel [256][32] LDS-resident.
// Loop n in chunks of 64: phase A recompute S[64n][32m] -> E in LDS; phase B
// accumulate O[256c][32m] += f_d · E with float4 global loads of f_d.
// LDS: 32KB (XmT) + 16KB (Xn) + 9KB (E, stride 36 to dodge bank conflicts) = 57KB.
// ---------------------------------------------------------------------------
__global__ __launch_bounds__(256) void out_kernel(const float* __restrict__ fm,
                                                  const float* __restrict__ fd,
                                                  const float* __restrict__ diag,
                                                  const float* __restrict__ w,
                                                  float* __restrict__ out) {
    __shared__ float XmT[C_][32];
    __shared__ float Xn[64][64];
    __shared__ float E[64][36];   // stride 36: float4-aligned, bank-conflict-free
    const int b  = blockIdx.y;
    const int m0 = blockIdx.x * 32;
    const size_t base = (size_t)b * C_ * N_;
    const int t = threadIdx.x;

    {   // load Xm panel: all 256 c rows, 32 m cols (32 elts/thread)
        int col = t & 31;
        int r0  = t >> 5;                // 0..7
        for (int c = r0; c < C_; c += 8) {
            size_t idx = base + (size_t)c * N_ + (m0 + col);
            XmT[c][col] = fm[idx] + fd[idx];
        }
    }

    const int tx = t & 15;   // phase A: cols tx*2, tx*2+1
    const int ty = t >> 4;   // phase A: rows ty*4 .. ty*4+3
    const int tm = t & 7;    // phase B: cols tm*4 .. tm*4+3
    const int tc = t >> 3;   // phase B: rows tc + 32*i, i=0..7
    float acc[8][4] = {};

    for (int n0 = 0; n0 < N_; n0 += 64) {
        // ---- phase A: S[64n][32m] over K=256 (chunks of 64) ----
        float s[4][2] = {};
        for (int kc = 0; kc < C_; kc += 64) {
            __syncthreads();   // also fences previous phase B's E reads
            {   // stage Xn chunk: rows c=kc..kc+63, cols n0..n0+63 (16/thread)
                int col = t & 63;
                int r0  = t >> 6;        // 0..3
                #pragma unroll
                for (int r = r0; r < 64; r += 4) {
                    size_t idx = base + (size_t)(kc + r) * N_ + (n0 + col);
                    Xn[r][col] = fm[idx] + fd[idx];
                }
            }
            __syncthreads();
            #pragma unroll 8
            for (int k = 0; k < 64; ++k) {
                float4 a  = *(const float4*)(&Xn[k][ty * 4]);
                float2 bb = *(const float2*)(&XmT[kc + k][tx * 2]);
                float av[4] = {a.x, a.y, a.z, a.w};
                #pragma unroll
                for (int i = 0; i < 4; ++i) {
                    s[i][0] = fmaf(av[i], bb.x, s[i][0]);
                    s[i][1] = fmaf(av[i], bb.y, s[i][1]);
                }
            }
        }
        // ---- E = w[n] * exp(S - diag[n]) ----
        #pragma unroll
        for (int i = 0; i < 4; ++i) {
            int n = n0 + ty * 4 + i;
            float dd = diag[b * N_ + n];
            float ww = w[b * N_ + n];
            E[ty * 4 + i][tx * 2 + 0] = __expf(s[i][0] - dd) * ww;
            E[ty * 4 + i][tx * 2 + 1] = __expf(s[i][1] - dd) * ww;
        }
        __syncthreads();
        // ---- phase B: O[c][m] += sum_{n in chunk} f_d[c][n] * E[n][m] ----
        #pragma unroll 2
        for (int n = 0; n < 64; n += 4) {
            float4 e0 = *(const float4*)(&E[n + 0][tm * 4]);
            float4 e1 = *(const float4*)(&E[n + 1][tm * 4]);
            float4 e2 = *(const float4*)(&E[n + 2][tm * 4]);
            float4 e3 = *(const float4*)(&E[n + 3][tm * 4]);
            float ev[4][4] = {{e0.x, e0.y, e0.z, e0.w},
                              {e1.x, e1.y, e1.z, e1.w},
                              {e2.x, e2.y, e2.z, e2.w},
                              {e3.x, e3.y, e3.z, e3.w}};
            #pragma unroll
            for (int i = 0; i < 8; ++i) {
                const float4 d4 = *(const float4*)(fd + base + (size_t)(tc + 32 * i) * N_ + (n0 + n));
                float dv[4] = {d4.x, d4.y, d4.z, d4.w};
                #pragma unroll
                for (int q = 0; q < 4; ++q) {
                    #pragma unroll
                    for (int j = 0; j < 4; ++j)
                        acc[i][j] = fmaf(dv[q], ev[q][j], acc[i][j]);
                }
            }
        }
    }
    // ---- epilogue: + f_d residual, store ----
    #pragma unroll
    for (int i = 0; i < 8; ++i) {
        size_t o = base + (size_t)(tc + 32 * i) * N_ + (m0 + tm * 4);
        const float4 r4 = *(const float4*)(fd + o);
        float4 o4;
        o4.x = acc[i][0] + r4.x;
        o4.y = acc[i][1] + r4.y;
        o4.z = acc[i][2] + r4.z;
        o4.w = acc[i][3] + r4.w;
        *(float4*)(out + o) = o4;
    }
}

// ---------------------------------------------------------------------------
extern "C" void kernel_launch(void* const* d_in, const int* in_sizes, int n_in,
                              void* d_out, int out_size, void* d_ws, size_t ws_size,
                              hipStream_t stream) {
    const float* fm = (const float*)d_in[0];
    const float* fd = (const float*)d_in[1];
    float* outp = (float*)d_out;
    float* diag = (float*)d_ws;                 // B_*N_ floats
    float* w    = diag + (size_t)B_ * N_;       // B_*N_ floats (128 KB total)

    diag_kernel<<<dim3((B_ * N_) / 64), dim3(64), 0, stream>>>(fm, fd, diag);
    lsum_kernel<<<dim3(N_ / 64, B_), dim3(512), 0, stream>>>(fm, fd, diag, w);
    out_kernel<<<dim3(N_ / 32, B_), dim3(256), 0, stream>>>(fm, fd, diag, w, outp);
}

// Round 2
// 305.360 us; speedup vs baseline: 8.2141x; 8.2141x over previous
//
#include <hip/hip_runtime.h>
#include <math.h>

#define B_ 4
#define C_ 256
#define N_ 4096   // H*W
#define LDA 264   // padded row stride (ushorts) for 256-wide c panels
#define LDF 72    // padded row stride (ushorts) for 64-wide n panels

typedef __attribute__((ext_vector_type(8))) short short8;
typedef __attribute__((ext_vector_type(4))) float f32x4;

__device__ inline ushort f2bf(float f) {
    uint u = __float_as_uint(f);
    return (ushort)((u + 0x7fffu + ((u >> 16) & 1u)) >> 16);   // RNE
}
__device__ inline float bflo(uint w) { return __uint_as_float(w << 16); }
__device__ inline float bfhi(uint w) { return __uint_as_float(w & 0xffff0000u); }

// ---------------------------------------------------------------------------
// P0: xbT[b][n][c] = bf16(fm+fd)  (transposed),  fdb[b][c][n] = bf16(fd)
// Grid (N/64, C/64, B) x 256. Register-level 4x4 transpose, no LDS.
// ---------------------------------------------------------------------------
__global__ __launch_bounds__(256) void prep_kernel(const float* __restrict__ fm,
                                                   const float* __restrict__ fd,
                                                   ushort* __restrict__ xbT,
                                                   ushort* __restrict__ fdb) {
    const int b = blockIdx.z, c0 = blockIdx.y * 64, n0 = blockIdx.x * 64;
    const int t = threadIdx.x;
    const int n4 = n0 + (t & 15) * 4;
    const int c4 = c0 + (t >> 4) * 4;
    const size_t base = (size_t)b * C_ * N_;
    float v[4][4];  // [j=c offset][i=n offset]
    #pragma unroll
    for (int j = 0; j < 4; ++j) {
        const float4 m4 = *(const float4*)(fm + base + (size_t)(c4 + j) * N_ + n4);
        const float4 d4 = *(const float4*)(fd + base + (size_t)(c4 + j) * N_ + n4);
        v[j][0] = m4.x + d4.x; v[j][1] = m4.y + d4.y;
        v[j][2] = m4.z + d4.z; v[j][3] = m4.w + d4.w;
        ushort4 fo; fo.x = f2bf(d4.x); fo.y = f2bf(d4.y); fo.z = f2bf(d4.z); fo.w = f2bf(d4.w);
        *(ushort4*)(fdb + base + (size_t)(c4 + j) * N_ + n4) = fo;
    }
    #pragma unroll
    for (int i = 0; i < 4; ++i) {
        ushort4 xo;
        xo.x = f2bf(v[0][i]); xo.y = f2bf(v[1][i]);
        xo.z = f2bf(v[2][i]); xo.w = f2bf(v[3][i]);
        *(ushort4*)(xbT + ((size_t)b * N_ + (n4 + i)) * C_ + c4) = xo;
    }
}

// ---------------------------------------------------------------------------
// P1: dg[b*N+n] = sum_c bf16(x)^2  (fp32 accumulate — matches MFMA S[n,n])
// ---------------------------------------------------------------------------
__global__ __launch_bounds__(256) void diag_kernel(const ushort* __restrict__ xbT,
                                                   float* __restrict__ dg) {
    const int gid = blockIdx.x * 256 + threadIdx.x;   // 0..B*N-1
    const ushort* row = xbT + (size_t)gid * C_;
    float s = 0.f;
    #pragma unroll 4
    for (int c = 0; c < C_; c += 8) {
        const uint4 w4 = *(const uint4*)(row + c);
        float f;
        f = bflo(w4.x); s = fmaf(f, f, s); f = bfhi(w4.x); s = fmaf(f, f, s);
        f = bflo(w4.y); s = fmaf(f, f, s); f = bfhi(w4.y); s = fmaf(f, f, s);
        f = bflo(w4.z); s = fmaf(f, f, s); f = bfhi(w4.z); s = fmaf(f, f, s);
        f = bflo(w4.w); s = fmaf(f, f, s); f = bfhi(w4.w); s = fmaf(f, f, s);
    }
    dg[gid] = s;
}

// ---------------------------------------------------------------------------
// K2: lsum[b*N+n] += sum_m exp(S[n,m] - dg[n])   (MFMA Gram, atomicAdd merge)
// 512 thr (8 waves): wave (wn=w&1 -> 32n strip, wm=w>>1 -> 16m tile).
// XnP A-frags preloaded to registers (invariant over m); per m-chunk only
// B-frag reads + staging.
// ---------------------------------------------------------------------------
__global__ __launch_bounds__(512, 2) void lsum_kernel(const ushort* __restrict__ xbT,
                                                      const float* __restrict__ dg,
                                                      float* __restrict__ lsum) {
    extern __shared__ ushort sm[];
    ushort* XnP = sm;              // [64][LDA]
    ushort* XmT = sm + 64 * LDA;   // [64][LDA]
    const int b = blockIdx.y, n0 = blockIdx.x * 64;
    const int t = threadIdx.x;
    const size_t xbase = (size_t)b * N_ * C_;
    #pragma unroll
    for (int j = 0; j < 4; ++j) {           // stage XnP: 2048 16B chunks
        const int cid = t + 512 * j;
        const int r = cid >> 5, col = cid & 31;
        *(uint4*)(XnP + r * LDA + col * 8) =
            *(const uint4*)(xbT + xbase + (size_t)(n0 + r) * C_ + col * 8);
    }
    const int lane = t & 63, w = t >> 6;
    const int l15 = lane & 15, q = lane >> 4;
    const int wn = w & 1, wm = w >> 1;
    float dv[2][4];
    #pragma unroll
    for (int i = 0; i < 2; ++i)
        #pragma unroll
        for (int r = 0; r < 4; ++r)
            dv[i][r] = dg[b * N_ + n0 + 32 * wn + 16 * i + 4 * q + r];
    __syncthreads();
    short8 af[2][8];
    #pragma unroll
    for (int i = 0; i < 2; ++i)
        #pragma unroll
        for (int kk = 0; kk < 8; ++kk)
            af[i][kk] = *(const short8*)(XnP + (32 * wn + 16 * i + l15) * LDA + kk * 32 + q * 8);
    float rs[2][4] = {};
    for (int m0 = 0; m0 < N_; m0 += 64) {
        __syncthreads();
        #pragma unroll
        for (int j = 0; j < 4; ++j) {       // stage XmT chunk
            const int cid = t + 512 * j;
            const int r = cid >> 5, col = cid & 31;
            *(uint4*)(XmT + r * LDA + col * 8) =
                *(const uint4*)(xbT + xbase + (size_t)(m0 + r) * C_ + col * 8);
        }
        __syncthreads();
        f32x4 acc0 = {0.f, 0.f, 0.f, 0.f}, acc1 = {0.f, 0.f, 0.f, 0.f};
        #pragma unroll
        for (int kk = 0; kk < 8; ++kk) {
            const short8 bb = *(const short8*)(XmT + (16 * wm + l15) * LDA + kk * 32 + q * 8);
            acc0 = __builtin_amdgcn_mfma_f32_16x16x32_bf16(af[0][kk], bb, acc0, 0, 0, 0);
            acc1 = __builtin_amdgcn_mfma_f32_16x16x32_bf16(af[1][kk], bb, acc1, 0, 0, 0);
        }
        #pragma unroll
        for (int r = 0; r < 4; ++r) {
            rs[0][r] += __expf(acc0[r] - dv[0][r]);
            rs[1][r] += __expf(acc1[r] - dv[1][r]);
        }
    }
    #pragma unroll
    for (int off = 1; off < 16; off <<= 1) {
        #pragma unroll
        for (int i = 0; i < 2; ++i)
            #pragma unroll
            for (int r = 0; r < 4; ++r)
                rs[i][r] += __shfl_xor(rs[i][r], off, 64);
    }
    if (l15 == 0) {
        #pragma unroll
        for (int i = 0; i < 2; ++i)
            #pragma unroll
            for (int r = 0; r < 4; ++r)
                atomicAdd(lsum + b * N_ + n0 + 32 * wn + 16 * i + 4 * q + r, rs[i][r]);
    }
}

// ---------------------------------------------------------------------------
// P3: g = d + log(l)   (so E = exp(S - g), one fused shift)
// ---------------------------------------------------------------------------
__global__ __launch_bounds__(256) void g_kernel(const float* __restrict__ dg,
                                                float* __restrict__ lg) {
    const int gid = blockIdx.x * 256 + threadIdx.x;
    lg[gid] = dg[gid] + __logf(lg[gid]);
}

// ---------------------------------------------------------------------------
// K3: out[c,m] = sum_n fd[c,n] * exp(S[n,m]-g[n]) + fd[c,m]
// 512 thr, grid (N/64, B). Persistent XmT panel (B-frags in registers).
// Per 64-n chunk: stage XnT->SB, MFMA S, exp->ET(bf16), stage FdT->SB,
// MFMA out += FdT*ET. Epilogue adds fp32 residual.
// ---------------------------------------------------------------------------
__global__ __launch_bounds__(512, 2) void out_kernel(const ushort* __restrict__ xbT,
                                                     const ushort* __restrict__ fdb,
                                                     const float* __restrict__ gg,
                                                     const float* __restrict__ fd32,
                                                     float* __restrict__ outp) {
    extern __shared__ ushort sm[];
    ushort* XmT = sm;                    // [64][LDA] persistent m-panel
    ushort* SB  = sm + 64 * LDA;         // XnT [64][LDA] (phase A) / FdT [256][LDF] (phase C)
    ushort* ET  = SB + 256 * LDF;        // [64 m][LDF] bf16 E^T
    const int b = blockIdx.y, m0 = blockIdx.x * 64;
    const int t = threadIdx.x, lane = t & 63, w = t >> 6;
    const int l15 = lane & 15, q = lane >> 4;
    const size_t xbase = (size_t)b * N_ * C_;
    #pragma unroll
    for (int j = 0; j < 4; ++j) {        // stage XmT
        const int cid = t + 512 * j;
        const int r = cid >> 5, col = cid & 31;
        *(uint4*)(XmT + r * LDA + col * 8) =
            *(const uint4*)(xbT + xbase + (size_t)(m0 + r) * C_ + col * 8);
    }
    __syncthreads();
    const int wn = w & 3, wm = w >> 2;   // phase A: 16n strip, 32m half
    short8 bfr[2][8];                    // persistent B-frags of XmT
    #pragma unroll
    for (int jt = 0; jt < 2; ++jt)
        #pragma unroll
        for (int kk = 0; kk < 8; ++kk)
            bfr[jt][kk] = *(const short8*)(XmT + (32 * wm + 16 * jt + l15) * LDA + kk * 32 + q * 8);
    f32x4 acc_o[2][4];
    #pragma unroll
    for (int ci = 0; ci < 2; ++ci)
        #pragma unroll
        for (int mj = 0; mj < 4; ++mj)
            acc_o[ci][mj] = (f32x4){0.f, 0.f, 0.f, 0.f};

    for (int n0 = 0; n0 < N_; n0 += 64) {
        #pragma unroll
        for (int j = 0; j < 4; ++j) {    // stage XnT -> SB
            const int cid = t + 512 * j;
            const int r = cid >> 5, col = cid & 31;
            *(uint4*)(SB + r * LDA + col * 8) =
                *(const uint4*)(xbT + xbase + (size_t)(n0 + r) * C_ + col * 8);
        }
        __syncthreads();
        // ---- phase A: S[16wn..+16][32wm..+32] ----
        f32x4 acc0 = {0.f, 0.f, 0.f, 0.f}, acc1 = {0.f, 0.f, 0.f, 0.f};
        #pragma unroll
        for (int kk = 0; kk < 8; ++kk) {
            const short8 a = *(const short8*)(SB + (16 * wn + l15) * LDA + kk * 32 + q * 8);
            acc0 = __builtin_amdgcn_mfma_f32_16x16x32_bf16(a, bfr[0][kk], acc0, 0, 0, 0);
            acc1 = __builtin_amdgcn_mfma_f32_16x16x32_bf16(a, bfr[1][kk], acc1, 0, 0, 0);
        }
        // ---- phase B: E^T = bf16(exp(S - g[n])) ----
        float gv[4];
        {
            const int nb = b * N_ + n0 + 16 * wn + 4 * q;
            #pragma unroll
            for (int r = 0; r < 4; ++r) gv[r] = gg[nb + r];
        }
        {
            ushort4 ev;
            int ml = 32 * wm + l15;
            ev.x = f2bf(__expf(acc0[0] - gv[0])); ev.y = f2bf(__expf(acc0[1] - gv[1]));
            ev.z = f2bf(__expf(acc0[2] - gv[2])); ev.w = f2bf(__expf(acc0[3] - gv[3]));
            *(ushort4*)(ET + ml * LDF + 16 * wn + 4 * q) = ev;
            ml = 32 * wm + 16 + l15;
            ev.x = f2bf(__expf(acc1[0] - gv[0])); ev.y = f2bf(__expf(acc1[1] - gv[1]));
            ev.z = f2bf(__expf(acc1[2] - gv[2])); ev.w = f2bf(__expf(acc1[3] - gv[3]));
            *(ushort4*)(ET + ml * LDF + 16 * wn + 4 * q) = ev;
        }
        __syncthreads();
        #pragma unroll
        for (int j = 0; j < 4; ++j) {    // stage FdT -> SB (overwrites XnT)
            const int cid = t + 512 * j;
            const int r = cid >> 3, col = cid & 7;
            *(uint4*)(SB + r * LDF + col * 8) =
                *(const uint4*)(fdb + xbase + (size_t)r * N_ + n0 + col * 8);
        }
        __syncthreads();
        // ---- phase C: out[32w..+32][m0..+64] += FdT * ET ----
        #pragma unroll
        for (int kk = 0; kk < 2; ++kk) {
            const short8 fa0 = *(const short8*)(SB + (32 * w + l15) * LDF + kk * 32 + q * 8);
            const short8 fa1 = *(const short8*)(SB + (32 * w + 16 + l15) * LDF + kk * 32 + q * 8);
            #pragma unroll
            for (int mj = 0; mj < 4; ++mj) {
                const short8 fb = *(const short8*)(ET + (16 * mj + l15) * LDF + kk * 32 + q * 8);
                acc_o[0][mj] = __builtin_amdgcn_mfma_f32_16x16x32_bf16(fa0, fb, acc_o[0][mj], 0, 0, 0);
                acc_o[1][mj] = __builtin_amdgcn_mfma_f32_16x16x32_bf16(fa1, fb, acc_o[1][mj], 0, 0, 0);
            }
        }
        __syncthreads();
    }
    // ---- epilogue: + fp32 residual ----
    #pragma unroll
    for (int ci = 0; ci < 2; ++ci)
        #pragma unroll
        for (int mj = 0; mj < 4; ++mj)
            #pragma unroll
            for (int r = 0; r < 4; ++r) {
                const int c = 32 * w + 16 * ci + 4 * q + r;
                const int m = m0 + 16 * mj + l15;
                const size_t o = xbase + (size_t)c * N_ + m;
                outp[o] = acc_o[ci][mj][r] + fd32[o];
            }
}

// ---------------------------------------------------------------------------
extern "C" void kernel_launch(void* const* d_in, const int* in_sizes, int n_in,
                              void* d_out, int out_size, void* d_ws, size_t ws_size,
                              hipStream_t stream) {
    const float* fm = (const float*)d_in[0];
    const float* fd = (const float*)d_in[1];
    float* outp = (float*)d_out;

    const size_t xb_elts = (size_t)B_ * N_ * C_;
    const size_t need = xb_elts * 2 * 2 + (size_t)B_ * N_ * 4 * 2;  // ~16.9 MB
    if (ws_size < need) return;  // loud failure rather than corruption

    ushort* xbT = (ushort*)d_ws;
    ushort* fdb = xbT + xb_elts;
    float*  dg  = (float*)(fdb + xb_elts);
    float*  lg  = dg + (size_t)B_ * N_;

    hipFuncSetAttribute(reinterpret_cast<const void*>(lsum_kernel),
                        hipFuncAttributeMaxDynamicSharedMemorySize, 2 * 64 * LDA * 2);
    hipFuncSetAttribute(reinterpret_cast<const void*>(out_kernel),
                        hipFuncAttributeMaxDynamicSharedMemorySize,
                        (64 * LDA + 256 * LDF + 64 * LDF) * 2);

    prep_kernel<<<dim3(N_ / 64, C_ / 64, B_), 256, 0, stream>>>(fm, fd, xbT, fdb);
    diag_kernel<<<dim3(B_ * N_ / 256), 256, 0, stream>>>(xbT, dg);
    hipMemsetAsync(lg, 0, (size_t)B_ * N_ * sizeof(float), stream);
    lsum_kernel<<<dim3(N_ / 64, B_), 512, 2 * 64 * LDA * 2, stream>>>(xbT, dg, lg);
    g_kernel<<<dim3(B_ * N_ / 256), 256, 0, stream>>>(dg, lg);
    out_kernel<<<dim3(N_ / 64, B_), 512, (64 * LDA + 256 * LDF + 64 * LDF) * 2, stream>>>(
        xbT, fdb, lg, fd, outp);
}